// Round 5
// baseline (1413.333 us; speedup 1.0000x reference)
//
#include <hip/hip_runtime.h>
#include <hip/hip_bf16.h>
#include <stdint.h>

typedef unsigned short u16;
typedef unsigned int u32;

#define T_TOK 8192
#define H_DIM 1024
#define I_DIM 2816
#define NE 8

typedef __bf16 bf16x8 __attribute__((ext_vector_type(8)));
typedef float f32x4 __attribute__((ext_vector_type(4)));

union F8 { uint4 v; bf16x8 f; u32 w[4]; };

__device__ __forceinline__ u16 f2bf(float f) {
    u32 u = __float_as_uint(f);
    u32 r = u + 0x7FFFu + ((u >> 16) & 1u);
    return (u16)(r >> 16);
}
// pack two f32 -> one dword of two bf16 (lo = a, hi = b); RNE
__device__ __forceinline__ u32 pkbf(float a, float b) {
    float2 f; f.x = a; f.y = b;
    __hip_bfloat162 h = __float22bfloat162_rn(f);
    union { __hip_bfloat162 h2; u32 w; } cv; cv.h2 = h;
    return cv.w;
}

// ---------------- zero cnt + out0 (f32 accumulator region of d_out) ----------------
__global__ void __launch_bounds__(256) zero_kernel(int* __restrict__ cnt, float* __restrict__ out0) {
    int gid = blockIdx.x * 256 + threadIdx.x;
    f32x4 z = {0.f, 0.f, 0.f, 0.f};
    ((f32x4*)out0)[gid] = z;
    if (blockIdx.x == 0 && threadIdx.x < NE) cnt[threadIdx.x] = 0;
}

// ---------------- router (f32): logits(f32 out) + softmax top-2 + expert lists ----------------
__global__ void __launch_bounds__(256)
router_kernel(const float* __restrict__ x, const float* __restrict__ gw,
              float* __restrict__ logits_out, float* __restrict__ wbuf,
              int* __restrict__ cnt, int* __restrict__ idxlist) {
    int lane = threadIdx.x & 63;
    int t = blockIdx.x * 4 + (threadIdx.x >> 6);
    const float* xr = x + (size_t)t * H_DIM;
    float acc[NE];
#pragma unroll
    for (int e = 0; e < NE; e++) acc[e] = 0.f;
#pragma unroll
    for (int i = 0; i < 16; i++) {
        int hh = i * 64 + lane;
        float xv = xr[hh];
        const float4* grow = (const float4*)(gw + (size_t)hh * NE);
        float4 g0 = grow[0], g1 = grow[1];
        acc[0] += xv * g0.x; acc[1] += xv * g0.y;
        acc[2] += xv * g0.z; acc[3] += xv * g0.w;
        acc[4] += xv * g1.x; acc[5] += xv * g1.y;
        acc[6] += xv * g1.z; acc[7] += xv * g1.w;
    }
#pragma unroll
    for (int m = 32; m >= 1; m >>= 1) {
#pragma unroll
        for (int e = 0; e < NE; e++) acc[e] += __shfl_xor(acc[e], m, 64);
    }
    if (lane == 0) {
        float mx = acc[0];
#pragma unroll
        for (int e = 1; e < NE; e++) mx = fmaxf(mx, acc[e]);
        float p[NE];
#pragma unroll
        for (int e = 0; e < NE; e++) p[e] = __expf(acc[e] - mx);
        float4 l0, l1;
        l0.x = acc[0]; l0.y = acc[1]; l0.z = acc[2]; l0.w = acc[3];
        l1.x = acc[4]; l1.y = acc[5]; l1.z = acc[6]; l1.w = acc[7];
        float4* lrow_p = (float4*)(logits_out + (size_t)t * NE);
        lrow_p[0] = l0; lrow_p[1] = l1;
        int a = 0; float pa = p[0];
#pragma unroll
        for (int e = 1; e < NE; e++) if (p[e] > pa) { a = e; pa = p[e]; }
        int b = -1; float pb = -1.f;
#pragma unroll
        for (int e = 0; e < NE; e++) if (e != a && p[e] > pb) { b = e; pb = p[e]; }
        if (b < 0) { b = a ^ 1; pb = p[b]; }   // defensive: never index with -1
        float inv = 1.f / (pa + pb);
        wbuf[2 * t]     = pa * inv;
        wbuf[2 * t + 1] = pb * inv;
        int pos = atomicAdd(&cnt[a], 1); idxlist[a * T_TOK + pos] = 2 * t;
        pos = atomicAdd(&cnt[b], 1);     idxlist[b * T_TOK + pos] = 2 * t + 1;
    }
}

// ---------------- grouped gate+up GEMM (I-chunk), f32 inputs -> bf16 MFMA ----------------
// Tile 128x128, BK=64. A: gathered x rows, cvt->bf16, swizzled b128 LDS.
// B: weights [K][N] f32, cvt->k-pair packed bf16 LDS (pitch 132 dwords).
__global__ void __launch_bounds__(256)
gateup_kernel(const float* __restrict__ x, const float* __restrict__ wg,
              const float* __restrict__ wu, const int* __restrict__ cnt,
              const int* __restrict__ idxlist, u16* __restrict__ hchunk,
              int nbase, int nlen) {
    int e = blockIdx.z;
    int c = cnt[e];
    int m0 = blockIdx.y * 128;
    if (m0 >= c) return;
    int n0g = nbase + blockIdx.x * 128;
    int n0l = blockIdx.x * 128;
    __shared__ alignas(16) u16 sA[128 * 64];
    __shared__ alignas(16) u32 sBg[32 * 132];
    __shared__ alignas(16) u32 sBu[32 * 132];
    int tid = threadIdx.x;

    int arow_lo = tid >> 3;
    int acg = ((tid & 7) ^ (arow_lo & 7)) * 8;   // element offset (8 f32 = 32B)
    const float* aP[4];
#pragma unroll
    for (int p = 0; p < 4; p++) {
        int j = m0 + arow_lo + 32 * p; if (j > c - 1) j = c - 1;
        int slot = idxlist[e * T_TOK + j];
        aP[p] = x + (size_t)(slot >> 1) * H_DIM + acg;
    }
    const float *bgP[2], *buP[2];
    int bDst[2];
#pragma unroll
    for (int p2 = 0; p2 < 2; p2++) {
        int q = p2 * 256 + tid;
        int k2 = q >> 4, n8 = q & 15;
        size_t off = ((size_t)e * H_DIM + 2 * k2) * I_DIM + n0g + n8 * 8;
        bgP[p2] = wg + off;
        buP[p2] = wu + off;
        bDst[p2] = k2 * 132 + n8 * 8;
    }

    int lane = tid & 63;
    int wm = (tid >> 7) & 1, wn = (tid >> 6) & 1;
    int lrow = lane & 15, quad = lane >> 4;
    f32x4 zero = {0.f, 0.f, 0.f, 0.f};
    f32x4 accg[4][4], accu[4][4];
#pragma unroll
    for (int mi = 0; mi < 4; mi++)
#pragma unroll
        for (int ni = 0; ni < 4; ni++) { accg[mi][ni] = zero; accu[mi][ni] = zero; }

    for (int k0 = 0; k0 < H_DIM; k0 += 64) {
        uint4 av[4];
#pragma unroll
        for (int p = 0; p < 4; p++) {
            const float4* ap = (const float4*)(aP[p] + k0);
            float4 lo = ap[0], hi = ap[1];
            av[p].x = pkbf(lo.x, lo.y); av[p].y = pkbf(lo.z, lo.w);
            av[p].z = pkbf(hi.x, hi.y); av[p].w = pkbf(hi.z, hi.w);
        }
        uint4 pg[2][2], pu[2][2];
#pragma unroll
        for (int p2 = 0; p2 < 2; p2++) {
            {
                const float4* r0 = (const float4*)(bgP[p2] + (size_t)k0 * I_DIM);
                const float4* r1 = (const float4*)(bgP[p2] + (size_t)(k0 + 1) * I_DIM);
                float4 a0 = r0[0], a1 = r0[1], b0 = r1[0], b1 = r1[1];
                pg[p2][0].x = pkbf(a0.x, b0.x); pg[p2][0].y = pkbf(a0.y, b0.y);
                pg[p2][0].z = pkbf(a0.z, b0.z); pg[p2][0].w = pkbf(a0.w, b0.w);
                pg[p2][1].x = pkbf(a1.x, b1.x); pg[p2][1].y = pkbf(a1.y, b1.y);
                pg[p2][1].z = pkbf(a1.z, b1.z); pg[p2][1].w = pkbf(a1.w, b1.w);
            }
            {
                const float4* r0 = (const float4*)(buP[p2] + (size_t)k0 * I_DIM);
                const float4* r1 = (const float4*)(buP[p2] + (size_t)(k0 + 1) * I_DIM);
                float4 a0 = r0[0], a1 = r0[1], b0 = r1[0], b1 = r1[1];
                pu[p2][0].x = pkbf(a0.x, b0.x); pu[p2][0].y = pkbf(a0.y, b0.y);
                pu[p2][0].z = pkbf(a0.z, b0.z); pu[p2][0].w = pkbf(a0.w, b0.w);
                pu[p2][1].x = pkbf(a1.x, b1.x); pu[p2][1].y = pkbf(a1.y, b1.y);
                pu[p2][1].z = pkbf(a1.z, b1.z); pu[p2][1].w = pkbf(a1.w, b1.w);
            }
        }
        __syncthreads();   // previous iteration's fragment reads complete
#pragma unroll
        for (int p = 0; p < 4; p++)
            *(uint4*)(sA + (size_t)(p * 256 + tid) * 8) = av[p];
#pragma unroll
        for (int p2 = 0; p2 < 2; p2++) {
            *(uint4*)(sBg + bDst[p2])     = pg[p2][0];
            *(uint4*)(sBg + bDst[p2] + 4) = pg[p2][1];
            *(uint4*)(sBu + bDst[p2])     = pu[p2][0];
            *(uint4*)(sBu + bDst[p2] + 4) = pu[p2][1];
        }
        __syncthreads();
#pragma unroll
        for (int kk = 0; kk < 2; kk++) {
            int cb = kk * 4 + quad;
            bf16x8 af[4]; F8 bg[4], bu[4];
#pragma unroll
            for (int i = 0; i < 4; i++) {
                int ra = wm * 64 + i * 16 + lrow;
                af[i] = *(const bf16x8*)(sA + (size_t)(ra * 8 + (cb ^ (ra & 7))) * 8);
                int n = wn * 64 + i * 16 + lrow;
                const u32* pb = sBg + (kk * 16 + quad * 4) * 132 + n;
                bg[i].w[0] = pb[0]; bg[i].w[1] = pb[132]; bg[i].w[2] = pb[264]; bg[i].w[3] = pb[396];
                const u32* pub = sBu + (kk * 16 + quad * 4) * 132 + n;
                bu[i].w[0] = pub[0]; bu[i].w[1] = pub[132]; bu[i].w[2] = pub[264]; bu[i].w[3] = pub[396];
            }
#pragma unroll
            for (int mi = 0; mi < 4; mi++)
#pragma unroll
                for (int ni = 0; ni < 4; ni++) {
                    accg[mi][ni] = __builtin_amdgcn_mfma_f32_16x16x32_bf16(af[mi], bg[ni].f, accg[mi][ni], 0, 0, 0);
                    accu[mi][ni] = __builtin_amdgcn_mfma_f32_16x16x32_bf16(af[mi], bu[ni].f, accu[mi][ni], 0, 0, 0);
                }
        }
    }
    // epilogue: h = silu(g)*u; C/D layout col=lane&15, row=quad*4+reg
#pragma unroll
    for (int mi = 0; mi < 4; mi++) {
#pragma unroll
        for (int r = 0; r < 4; r++) {
            int grow = m0 + wm * 64 + mi * 16 + quad * 4 + r;
            if (grow < c) {
                int slot = idxlist[e * T_TOK + grow];
                u16* hrow = hchunk + (size_t)slot * nlen + n0l + wn * 64 + lrow;
#pragma unroll
                for (int ni = 0; ni < 4; ni++) {
                    float g = accg[mi][ni][r], u = accu[mi][ni][r];
                    float hv = g * u / (1.f + __expf(-g));
                    hrow[ni * 16] = f2bf(hv);
                }
            }
        }
    }
}

// ---------------- grouped down GEMM chunk: out0 += w * h_chunk @ wd[e][kbase:kbase+klen] ----------------
__global__ void __launch_bounds__(256)
down_kernel(const u16* __restrict__ hchunk, const float* __restrict__ wd,
            const int* __restrict__ cnt, const int* __restrict__ idxlist,
            const float* __restrict__ wbuf, float* __restrict__ out0,
            int kbase, int klen) {
    int e = blockIdx.z;
    int c = cnt[e];
    int m0 = blockIdx.y * 128;
    if (m0 >= c) return;
    int n0 = blockIdx.x * 128;
    __shared__ alignas(16) u16 sA[128 * 64];
    __shared__ alignas(16) u32 sB[32 * 132];
    int tid = threadIdx.x;

    int arow_lo = tid >> 3;
    int acg = ((tid & 7) ^ (arow_lo & 7)) * 8;
    const u16* aP[4];
#pragma unroll
    for (int p = 0; p < 4; p++) {
        int j = m0 + arow_lo + 32 * p; if (j > c - 1) j = c - 1;
        int slot = idxlist[e * T_TOK + j];
        aP[p] = hchunk + (size_t)slot * klen + acg;
    }
    const float* bP[2];
    int bDst[2];
#pragma unroll
    for (int p2 = 0; p2 < 2; p2++) {
        int q = p2 * 256 + tid;
        int k2 = q >> 4, n8 = q & 15;
        bP[p2] = wd + ((size_t)e * I_DIM + kbase + 2 * k2) * H_DIM + n0 + n8 * 8;
        bDst[p2] = k2 * 132 + n8 * 8;
    }

    int lane = tid & 63;
    int wm = (tid >> 7) & 1, wn = (tid >> 6) & 1;
    int lrow = lane & 15, quad = lane >> 4;
    f32x4 zero = {0.f, 0.f, 0.f, 0.f};
    f32x4 acc[4][4];
#pragma unroll
    for (int mi = 0; mi < 4; mi++)
#pragma unroll
        for (int ni = 0; ni < 4; ni++) acc[mi][ni] = zero;

    for (int k0 = 0; k0 < klen; k0 += 64) {
        uint4 av[4];
#pragma unroll
        for (int p = 0; p < 4; p++) av[p] = *(const uint4*)(aP[p] + k0);
        uint4 pb_[2][2];
#pragma unroll
        for (int p2 = 0; p2 < 2; p2++) {
            const float4* r0 = (const float4*)(bP[p2] + (size_t)k0 * H_DIM);
            const float4* r1 = (const float4*)(bP[p2] + (size_t)(k0 + 1) * H_DIM);
            float4 a0 = r0[0], a1 = r0[1], b0 = r1[0], b1 = r1[1];
            pb_[p2][0].x = pkbf(a0.x, b0.x); pb_[p2][0].y = pkbf(a0.y, b0.y);
            pb_[p2][0].z = pkbf(a0.z, b0.z); pb_[p2][0].w = pkbf(a0.w, b0.w);
            pb_[p2][1].x = pkbf(a1.x, b1.x); pb_[p2][1].y = pkbf(a1.y, b1.y);
            pb_[p2][1].z = pkbf(a1.z, b1.z); pb_[p2][1].w = pkbf(a1.w, b1.w);
        }
        __syncthreads();
#pragma unroll
        for (int p = 0; p < 4; p++)
            *(uint4*)(sA + (size_t)(p * 256 + tid) * 8) = av[p];
#pragma unroll
        for (int p2 = 0; p2 < 2; p2++) {
            *(uint4*)(sB + bDst[p2])     = pb_[p2][0];
            *(uint4*)(sB + bDst[p2] + 4) = pb_[p2][1];
        }
        __syncthreads();
#pragma unroll
        for (int kk = 0; kk < 2; kk++) {
            int cb = kk * 4 + quad;
            bf16x8 af[4]; F8 bf[4];
#pragma unroll
            for (int i = 0; i < 4; i++) {
                int ra = wm * 64 + i * 16 + lrow;
                af[i] = *(const bf16x8*)(sA + (size_t)(ra * 8 + (cb ^ (ra & 7))) * 8);
                int n = wn * 64 + i * 16 + lrow;
                const u32* pb = sB + (kk * 16 + quad * 4) * 132 + n;
                bf[i].w[0] = pb[0]; bf[i].w[1] = pb[132]; bf[i].w[2] = pb[264]; bf[i].w[3] = pb[396];
            }
#pragma unroll
            for (int mi = 0; mi < 4; mi++)
#pragma unroll
                for (int ni = 0; ni < 4; ni++)
                    acc[mi][ni] = __builtin_amdgcn_mfma_f32_16x16x32_bf16(af[mi], bf[ni].f, acc[mi][ni], 0, 0, 0);
        }
    }
#pragma unroll
    for (int mi = 0; mi < 4; mi++) {
#pragma unroll
        for (int r = 0; r < 4; r++) {
            int grow = m0 + wm * 64 + mi * 16 + quad * 4 + r;
            if (grow < c) {
                int slot = idxlist[e * T_TOK + grow];
                float w = wbuf[slot];
                float* yrow = out0 + (size_t)(slot >> 1) * H_DIM + n0 + wn * 64 + lrow;
#pragma unroll
                for (int ni = 0; ni < 4; ni++)
                    atomicAdd(&yrow[ni * 16], w * acc[mi][ni][r]);
            }
        }
    }
}

extern "C" void kernel_launch(void* const* d_in, const int* in_sizes, int n_in,
                              void* d_out, int out_size, void* d_ws, size_t ws_size,
                              hipStream_t stream) {
    (void)in_sizes; (void)n_in; (void)out_size;
    const float* x  = (const float*)d_in[0];
    const float* gw = (const float*)d_in[1];
    const float* wg = (const float*)d_in[2];
    const float* wu = (const float*)d_in[3];
    const float* wd = (const float*)d_in[4];
    float* out = (float*)d_out;                       // f32 outputs, per reference dtype
    float* logits = out + (size_t)T_TOK * H_DIM;      // output 1: [T, E] f32
    char* ws = (char*)d_ws;

    size_t off = 0;
    int* cnt = (int*)(ws + off);       off += 256;
    int* idxlist = (int*)(ws + off);   off += (size_t)NE * T_TOK * 4;        // 256 KB
    float* wbuf = (float*)(ws + off);  off += (size_t)2 * T_TOK * 4;         // 64 KB
    // adaptive I-chunk width: largest multiple of 128 fitting in remaining ws
    int ich = I_DIM;
    while (ich > 128 && off + (size_t)2 * T_TOK * ich * 2 > ws_size) ich -= 128;
    u16* hchunk = (u16*)(ws + off);

    zero_kernel<<<T_TOK * H_DIM / 4 / 256, 256, 0, stream>>>(cnt, out);
    router_kernel<<<T_TOK / 4, 256, 0, stream>>>(x, gw, logits, wbuf, cnt, idxlist);
    for (int base = 0; base < I_DIM; base += ich) {
        int len = I_DIM - base; if (len > ich) len = ich;
        gateup_kernel<<<dim3(len / 128, 64, NE), 256, 0, stream>>>(x, wg, wu, cnt, idxlist, hchunk, base, len);
        down_kernel<<<dim3(H_DIM / 128, 64, NE), 256, 0, stream>>>(hchunk, wd, cnt, idxlist, wbuf, out, base, len);
    }
}